// Round 1
// baseline (337.217 us; speedup 1.0000x reference)
//
#include <hip/hip_runtime.h>
#include <math.h>

#define TB 16
#define TL 8192
#define TC 64
#define THC 256

constexpr float INV_BL = 1.0f / (16.0f * 8192.0f);
constexpr float EPSV = 1e-5f;
constexpr float INV_SQRT_H = 0.17677669529663687f; // 1/sqrt(32)

// workspace offsets (floats)
#define WS_G      0
#define WS_SX     65536
#define WS_STATS  66560   /* s1[64] s2[64] s1z[64] s2z[64] */
#define WS_M      66816
#define WS_N      132352
#define WS_A2E    197888  /* a2[64] e[64] */
#define WS_S1T    198016  /* [16][64][256] */
#define WS_V1     460160  /* [16][256*64]  */
#define WS_GPART  722304  /* [16][16][4096] */
#define WS_SXPART 1770880 /* [16][16][64]   */
#define WS_MPART  1787264 /* [4][16][4096]  */
// total 2049408 floats = 8.2 MB

__device__ __forceinline__ int swa(int l, int c){
  return l*64 + ((((c>>2) ^ (l&15))<<2) | (c&3));
}
__device__ __forceinline__ int gsw(int i, int j){
  return i*64 + ((((j>>2) ^ (i&15))<<2) | (j&3));
}
__device__ __forceinline__ int scidx(int i, int j){
  return i*20 + (j ^ ((i>>3)&15));
}

// ---------------- K1: Gram partials + row sums ----------------
__global__ __launch_bounds__(256) void k1_gram(const float* __restrict__ x,
                                               float* __restrict__ ws){
  __shared__ float xt[4096];
  __shared__ float gl[4096];
  const int b = blockIdx.y, chunk = blockIdx.x;
  const int t = threadIdx.x;
  const int cg = t>>4, m = t&15;
  const int grp = t>>6, ti = (t>>3)&7, tj = t&7;
  float acc[8][8];
  #pragma unroll
  for (int u=0;u<8;++u)
    #pragma unroll
    for (int v=0;v<8;++v) acc[u][v]=0.f;
  float sx[4] = {0.f,0.f,0.f,0.f};
  #pragma unroll
  for (int r=0;r<16;++r) gl[t+256*r]=0.f;
  const float* xb = x + b*TC*TL + chunk*512;
  for (int tile=0; tile<8; ++tile){
    const int l0 = tile*64;
    #pragma unroll
    for (int it=0; it<4; ++it){
      const int c = cg + 16*it;
      const float4 v = *(const float4*)(xb + c*TL + l0 + 4*m);
      sx[it] += v.x+v.y+v.z+v.w;
      const int l = 4*m;
      xt[swa(l+0,c)] = v.x;
      xt[swa(l+1,c)] = v.y;
      xt[swa(l+2,c)] = v.z;
      xt[swa(l+3,c)] = v.w;
    }
    __syncthreads();
    #pragma unroll 4
    for (int k=0;k<16;++k){
      const int l = grp*16 + k;
      const float4 xi0 = *(const float4*)&xt[swa(l, 8*ti)];
      const float4 xi1 = *(const float4*)&xt[swa(l, 8*ti+4)];
      const float4 xj0 = *(const float4*)&xt[swa(l, 8*tj)];
      const float4 xj1 = *(const float4*)&xt[swa(l, 8*tj+4)];
      const float xi[8] = {xi0.x,xi0.y,xi0.z,xi0.w, xi1.x,xi1.y,xi1.z,xi1.w};
      const float xj[8] = {xj0.x,xj0.y,xj0.z,xj0.w, xj1.x,xj1.y,xj1.z,xj1.w};
      #pragma unroll
      for (int u=0;u<8;++u)
        #pragma unroll
        for (int v=0;v<8;++v)
          acc[u][v] = fmaf(xi[u], xj[v], acc[u][v]);
    }
    __syncthreads();
  }
  #pragma unroll
  for (int u=0;u<8;++u)
    #pragma unroll
    for (int v=0;v<8;++v)
      atomicAdd(&gl[gsw(8*ti+u, 8*tj+v)], acc[u][v]);
  __syncthreads();
  float* Gp = ws + WS_GPART + (b*16 + chunk)*4096;
  #pragma unroll
  for (int r=0;r<16;++r){
    const int e = t + 256*r;
    Gp[e] = gl[gsw(e>>6, e&63)];
  }
  #pragma unroll
  for (int off=8; off>=1; off>>=1){
    sx[0] += __shfl_down(sx[0], off, 16);
    sx[1] += __shfl_down(sx[1], off, 16);
    sx[2] += __shfl_down(sx[2], off, 16);
    sx[3] += __shfl_down(sx[3], off, 16);
  }
  if (m==0){
    float* Sp = ws + WS_SXPART + (b*16+chunk)*64;
    Sp[cg]    = sx[0];
    Sp[cg+16] = sx[1];
    Sp[cg+32] = sx[2];
    Sp[cg+48] = sx[3];
  }
}

// ---------------- K1b: reduce partials, zero accumulators ----------------
__global__ __launch_bounds__(256) void k1b_reduce(float* __restrict__ ws){
  const int b = blockIdx.x, t = threadIdx.x;
  const float* Gp = ws + WS_GPART + b*16*4096;
  float* G = ws + WS_G + b*4096;
  #pragma unroll 4
  for (int r=0;r<16;++r){
    const int e = t + 256*r;
    float s = 0.f;
    #pragma unroll
    for (int ch=0;ch<16;++ch) s += Gp[ch*4096 + e];
    G[e] = s;
  }
  if (t < 64){
    const float* Sp = ws + WS_SXPART + b*16*64;
    float s = 0.f;
    #pragma unroll
    for (int ch=0; ch<16; ++ch) s += Sp[ch*64 + t];
    ws[WS_SX + b*64 + t] = s;
  }
  if (b==0) ws[WS_STATS + t] = 0.f;
  float* V1 = ws + WS_V1 + b*16384;
  #pragma unroll
  for (int r=0;r<64;++r) V1[t + 256*r] = 0.f;
}

// ---------------- K2A: S1^T = (wq G)^T ----------------
__global__ __launch_bounds__(256) void k2a_s1t(const float* __restrict__ wq,
                                               float* __restrict__ ws){
  __shared__ float Gt[64*68];
  const int b = blockIdx.y, iblk = blockIdx.x;
  const int t = threadIdx.x;
  const float* G = ws + WS_G + b*4096;
  #pragma unroll
  for (int r=0;r<4;++r){
    const int idx = r*1024 + t*4;
    *(float4*)&Gt[(idx>>6)*68 + (idx&63)] = *(const float4*)(G + idx);
  }
  __syncthreads();
  const int il = t>>2, cq = t&3;
  const int i = iblk*64 + il;
  const float* wqr = wq + i*64;
  float4 a0={0,0,0,0}, a1={0,0,0,0}, a2={0,0,0,0}, a3={0,0,0,0};
  #pragma unroll 8
  for (int k=0;k<64;++k){
    const float a = wqr[k];
    const float4 g0 = *(const float4*)&Gt[k*68 + cq*16 + 0];
    const float4 g1 = *(const float4*)&Gt[k*68 + cq*16 + 4];
    const float4 g2 = *(const float4*)&Gt[k*68 + cq*16 + 8];
    const float4 g3 = *(const float4*)&Gt[k*68 + cq*16 + 12];
    a0.x=fmaf(a,g0.x,a0.x); a0.y=fmaf(a,g0.y,a0.y); a0.z=fmaf(a,g0.z,a0.z); a0.w=fmaf(a,g0.w,a0.w);
    a1.x=fmaf(a,g1.x,a1.x); a1.y=fmaf(a,g1.y,a1.y); a1.z=fmaf(a,g1.z,a1.z); a1.w=fmaf(a,g1.w,a1.w);
    a2.x=fmaf(a,g2.x,a2.x); a2.y=fmaf(a,g2.y,a2.y); a2.z=fmaf(a,g2.z,a2.z); a2.w=fmaf(a,g2.w,a2.w);
    a3.x=fmaf(a,g3.x,a3.x); a3.y=fmaf(a,g3.y,a3.y); a3.z=fmaf(a,g3.z,a3.z); a3.w=fmaf(a,g3.w,a3.w);
  }
  float* S1T = ws + WS_S1T + b*16384;
  const int c0 = cq*16;
  S1T[(c0+ 0)*256 + i]=a0.x; S1T[(c0+ 1)*256 + i]=a0.y; S1T[(c0+ 2)*256 + i]=a0.z; S1T[(c0+ 3)*256 + i]=a0.w;
  S1T[(c0+ 4)*256 + i]=a1.x; S1T[(c0+ 5)*256 + i]=a1.y; S1T[(c0+ 6)*256 + i]=a1.z; S1T[(c0+ 7)*256 + i]=a1.w;
  S1T[(c0+ 8)*256 + i]=a2.x; S1T[(c0+ 9)*256 + i]=a2.y; S1T[(c0+10)*256 + i]=a2.z; S1T[(c0+11)*256 + i]=a2.w;
  S1T[(c0+12)*256 + i]=a3.x; S1T[(c0+13)*256 + i]=a3.y; S1T[(c0+14)*256 + i]=a3.z; S1T[(c0+15)*256 + i]=a3.w;
}

// ---------------- K2B: scores + column softmax + attn@wv -> V1 ----------------
__global__ __launch_bounds__(256) void k2b_attn_v1(const float* __restrict__ wk,
                                                   const float* __restrict__ wv,
                                                   float* __restrict__ ws){
  __shared__ float S1Tl[64*260];
  __shared__ float wkT[64*20];
  __shared__ float sc[5120];
  __shared__ float at[5120];
  __shared__ float wvl[16*68];
  __shared__ float cstat[32];
  const int b = blockIdx.y, jb = blockIdx.x;
  const int j0 = jb*16;
  const int t = threadIdx.x;
  #pragma unroll
  for (int r=0;r<20;++r) sc[t + 256*r] = 0.f;
  {
    const float* src = ws + WS_S1T + b*16384;
    const int c = t>>2, ir = (t&3)*64;
    #pragma unroll
    for (int r=0;r<16;++r){
      *(float4*)&S1Tl[c*260 + ir + 4*r] = *(const float4*)(src + c*256 + ir + 4*r);
    }
  }
  {
    const int j = t&15, c4 = (t>>4)*4;
    #pragma unroll
    for (int r=0;r<4;++r)
      wkT[(c4+r)*20 + j] = wk[(j0+j)*64 + c4 + r];
  }
  {
    const int j = t>>4, c4 = (t&15)*4;
    *(float4*)&wvl[j*68 + c4] = *(const float4*)(wv + (j0+j)*64 + c4);
  }
  __syncthreads();
  {
    const int grp = t>>6, ti = (t>>1)&31, tj = t&1;
    float acc[8][8];
    #pragma unroll
    for (int u=0;u<8;++u)
      #pragma unroll
      for (int v=0;v<8;++v) acc[u][v]=0.f;
    #pragma unroll 4
    for (int kk=0;kk<16;++kk){
      const int c = grp*16 + kk;
      const float4 A0 = *(const float4*)&S1Tl[c*260 + 8*ti];
      const float4 A1 = *(const float4*)&S1Tl[c*260 + 8*ti + 4];
      const float4 B0 = *(const float4*)&wkT[c*20 + 8*tj];
      const float4 B1 = *(const float4*)&wkT[c*20 + 8*tj + 4];
      const float Aa[8] = {A0.x,A0.y,A0.z,A0.w,A1.x,A1.y,A1.z,A1.w};
      const float Bb[8] = {B0.x,B0.y,B0.z,B0.w,B1.x,B1.y,B1.z,B1.w};
      #pragma unroll
      for (int u=0;u<8;++u)
        #pragma unroll
        for (int v=0;v<8;++v) acc[u][v] = fmaf(Aa[u],Bb[v],acc[u][v]);
    }
    #pragma unroll
    for (int u=0;u<8;++u)
      #pragma unroll
      for (int v=0;v<8;++v)
        atomicAdd(&sc[scidx(8*ti+u, 8*tj+v)], acc[u][v]);
  }
  __syncthreads();
  {
    const int jg = t>>4, ig = t&15;
    float mx = -3.0e38f;
    #pragma unroll 4
    for (int r=0;r<16;++r) mx = fmaxf(mx, sc[scidx(ig+16*r, jg)]);
    #pragma unroll
    for (int off=8; off>=1; off>>=1) mx = fmaxf(mx, __shfl_xor(mx, off, 16));
    float sum = 0.f;
    #pragma unroll 4
    for (int r=0;r<16;++r) sum += __expf(sc[scidx(ig+16*r, jg)] - mx);
    #pragma unroll
    for (int off=8; off>=1; off>>=1) sum += __shfl_xor(sum, off, 16);
    if (ig==0){ cstat[jg] = mx; cstat[16+jg] = 1.f/sum; }
  }
  __syncthreads();
  #pragma unroll
  for (int r=0;r<16;++r)
    at[scidx(t, r)] = __expf(sc[scidx(t, r)] - cstat[r]) * cstat[16+r];
  __syncthreads();
  {
    const int ti = t>>3, tc = t&7;
    float acc[8][8];
    #pragma unroll
    for (int u=0;u<8;++u)
      #pragma unroll
      for (int v=0;v<8;++v) acc[u][v]=0.f;
    #pragma unroll
    for (int j=0;j<16;++j){
      float Aa[8];
      #pragma unroll
      for (int u=0;u<8;++u) Aa[u] = at[scidx(8*ti+u, j)];
      const float4 B0 = *(const float4*)&wvl[j*68 + 8*tc];
      const float4 B1 = *(const float4*)&wvl[j*68 + 8*tc + 4];
      const float Bb[8] = {B0.x,B0.y,B0.z,B0.w,B1.x,B1.y,B1.z,B1.w};
      #pragma unroll
      for (int u=0;u<8;++u)
        #pragma unroll
        for (int v=0;v<8;++v) acc[u][v] = fmaf(Aa[u],Bb[v],acc[u][v]);
    }
    float* V1 = ws + WS_V1 + b*16384;
    #pragma unroll
    for (int u=0;u<8;++u)
      #pragma unroll
      for (int v=0;v<8;++v)
        atomicAdd(&V1[(8*ti+u)*64 + 8*tc + v], acc[u][v]);
  }
}

// ---- shared 64x64 LDS GEMM helper: C[a][b] += sum_k A[k][a]*B[k][b] ----
__device__ __forceinline__ void gemm64_tile(const float* Al, const float* Bl,
                                            float* cds, int t){
  const int grp = t>>6, ta = (t>>3)&7, tb = t&7;
  float acc[8][8];
  #pragma unroll
  for (int u=0;u<8;++u)
    #pragma unroll
    for (int v=0;v<8;++v) acc[u][v]=0.f;
  #pragma unroll 4
  for (int kk=0;kk<16;++kk){
    const int k = grp*16 + kk;
    const float4 A0 = *(const float4*)&Al[k*68 + 8*ta];
    const float4 A1 = *(const float4*)&Al[k*68 + 8*ta + 4];
    const float4 B0 = *(const float4*)&Bl[k*68 + 8*tb];
    const float4 B1 = *(const float4*)&Bl[k*68 + 8*tb + 4];
    const float Aa[8] = {A0.x,A0.y,A0.z,A0.w,A1.x,A1.y,A1.z,A1.w};
    const float Bb[8] = {B0.x,B0.y,B0.z,B0.w,B1.x,B1.y,B1.z,B1.w};
    #pragma unroll
    for (int u=0;u<8;++u)
      #pragma unroll
      for (int v=0;v<8;++v) acc[u][v] = fmaf(Aa[u],Bb[v],acc[u][v]);
  }
  #pragma unroll
  for (int u=0;u<8;++u)
    #pragma unroll
    for (int v=0;v<8;++v)
      atomicAdd(&cds[gsw(8*ta+u, 8*tb+v)], acc[u][v]);
}

// ---------------- K2D: M partials = wc @ V1 slice ----------------
__global__ __launch_bounds__(256) void k2d_mpart(const float* __restrict__ wc,
                                                 float* __restrict__ ws){
  __shared__ float wcT[64*68];
  __shared__ float V1l[64*68];
  __shared__ float ml[4096];
  const int b = blockIdx.y, ig = blockIdx.x;
  const int i0 = ig*64, t = threadIdx.x;
  #pragma unroll
  for (int r=0;r<16;++r) ml[t+256*r]=0.f;
  const float* V1 = ws + WS_V1 + b*16384 + i0*64;
  #pragma unroll
  for (int r=0;r<16;++r){
    const int e = t + 256*r;
    V1l[(e>>6)*68 + (e&63)] = V1[e];
  }
  {
    const int o = t>>2;
    #pragma unroll
    for (int r=0;r<4;++r){
      const float4 v = *(const float4*)(wc + o*256 + i0 + (t&3)*16 + 4*r);
      const int ii = (t&3)*16 + 4*r;
      wcT[(ii+0)*68 + o] = v.x;
      wcT[(ii+1)*68 + o] = v.y;
      wcT[(ii+2)*68 + o] = v.z;
      wcT[(ii+3)*68 + o] = v.w;
    }
  }
  __syncthreads();
  gemm64_tile(wcT, V1l, ml, t);
  __syncthreads();
  float* Mp = ws + WS_MPART + (ig*16 + b)*4096;
  #pragma unroll
  for (int r=0;r<16;++r){
    const int e = t + 256*r;
    Mp[e] = ml[gsw(e>>6, e&63)] * INV_SQRT_H;
  }
}

// ---------------- K2E: M + BN1 stats ----------------
__global__ __launch_bounds__(256) void k2e_stats1(float* __restrict__ ws){
  __shared__ float Ml[64*68], MlT[64*68], Gt[64*68];
  __shared__ float tl[4096];
  __shared__ float Sxl[64];
  const int b = blockIdx.x, t = threadIdx.x;
  #pragma unroll
  for (int r=0;r<16;++r) tl[t+256*r]=0.f;
  #pragma unroll
  for (int r=0;r<16;++r){
    const int e = t + 256*r;
    float s = 0.f;
    #pragma unroll
    for (int ig=0; ig<4; ++ig) s += ws[WS_MPART + (ig*16+b)*4096 + e];
    const int o = e>>6, k = e&63;
    Ml[o*68+k] = s;
    MlT[k*68+o] = s;
    ws[WS_M + b*4096 + e] = s;
  }
  const float* G = ws + WS_G + b*4096;
  #pragma unroll
  for (int r=0;r<4;++r){
    const int idx = r*1024 + t*4;
    *(float4*)&Gt[(idx>>6)*68 + (idx&63)] = *(const float4*)(G + idx);
  }
  if (t<64) Sxl[t] = ws[WS_SX + b*64 + t];
  __syncthreads();
  if (t<64){
    float v = 0.f;
    #pragma unroll 8
    for (int k=0;k<64;++k) v += Ml[t*68+k]*Sxl[k];
    atomicAdd(&ws[WS_STATS + t], v);
  }
  gemm64_tile(MlT, Gt, tl, t);
  __syncthreads();
  {
    const int c = t>>2, jq = t&3;
    float v = 0.f;
    #pragma unroll
    for (int jj=0;jj<16;++jj){
      const int j = jq*16 + jj;
      v += tl[gsw(c, j)] * Ml[c*68 + j];
    }
    v += __shfl_xor(v, 2, 4);
    v += __shfl_xor(v, 1, 4);
    if (jq==0) atomicAdd(&ws[WS_STATS + 64 + c], v);
  }
}

// ---------------- K2F: N + BN2 stats ----------------
__global__ __launch_bounds__(256) void k2f_n_stats2(const float* __restrict__ wl,
                                                    const float* __restrict__ g1,
                                                    float* __restrict__ ws){
  __shared__ float Ml[64*68], Gt[64*68], wlT[64*68], Nl[64*68], NlT[64*68];
  __shared__ float nl[4096], tl[4096];
  __shared__ float Sxl[64], a1l[64];
  const int b = blockIdx.x, t = threadIdx.x;
  #pragma unroll
  for (int r=0;r<16;++r){ nl[t+256*r]=0.f; tl[t+256*r]=0.f; }
  if (t<64){
    const float mean1 = ws[WS_STATS+t]*INV_BL;
    const float var1 = ws[WS_STATS+64+t]*INV_BL - mean1*mean1;
    a1l[t] = g1[t]*rsqrtf(var1 + EPSV);
    Sxl[t] = ws[WS_SX + b*64 + t];
  }
  #pragma unroll
  for (int r=0;r<16;++r){
    const int e = t + 256*r;
    Ml[(e>>6)*68 + (e&63)] = ws[WS_M + b*4096 + e];
  }
  const float* G = ws + WS_G + b*4096;
  #pragma unroll
  for (int r=0;r<4;++r){
    const int idx = r*1024 + t*4;
    *(float4*)&Gt[(idx>>6)*68 + (idx&63)] = *(const float4*)(G + idx);
  }
  __syncthreads();
  {
    const int o = t>>2;
    #pragma unroll
    for (int r=0;r<4;++r){
      const float4 v = *(const float4*)(wl + o*64 + (t&3)*16 + 4*r);
      const int cc = (t&3)*16 + 4*r;
      wlT[(cc+0)*68 + o] = v.x*a1l[cc+0];
      wlT[(cc+1)*68 + o] = v.y*a1l[cc+1];
      wlT[(cc+2)*68 + o] = v.z*a1l[cc+2];
      wlT[(cc+3)*68 + o] = v.w*a1l[cc+3];
    }
  }
  __syncthreads();
  gemm64_tile(wlT, Ml, nl, t);
  __syncthreads();
  #pragma unroll
  for (int r=0;r<16;++r){
    const int e = t + 256*r;
    const int o = e>>6, k = e&63;
    const float nv = nl[gsw(o,k)] + wl[e];
    ws[WS_N + b*4096 + e] = nv;
    Nl[o*68+k] = nv;
    NlT[k*68+o] = nv;
  }
  __syncthreads();
  if (t<64){
    float v=0.f;
    #pragma unroll 8
    for (int k=0;k<64;++k) v += Nl[t*68+k]*Sxl[k];
    atomicAdd(&ws[WS_STATS + 128 + t], v);
  }
  gemm64_tile(NlT, Gt, tl, t);
  __syncthreads();
  {
    const int o = t>>2, jq = t&3;
    float v = 0.f;
    #pragma unroll
    for (int jj=0;jj<16;++jj){
      const int j = jq*16 + jj;
      v += tl[gsw(o, j)] * Nl[o*68 + j];
    }
    v += __shfl_xor(v, 2, 4);
    v += __shfl_xor(v, 1, 4);
    if (jq==0) atomicAdd(&ws[WS_STATS + 192 + o], v);
  }
}

// ---------------- K2G: a2, e ----------------
__global__ __launch_bounds__(64) void k2g_final(const float* __restrict__ g2,
                                                const float* __restrict__ b2,
                                                float* __restrict__ ws){
  const int o = threadIdx.x;
  const float mu = ws[WS_STATS+128+o]*INV_BL;
  const float var2 = ws[WS_STATS+192+o]*INV_BL - mu*mu;
  const float a2 = g2[o]*rsqrtf(var2 + EPSV);
  ws[WS_A2E+o] = a2;
  ws[WS_A2E+64+o] = b2[o] - a2*mu;
}

// ---------------- K3: out = relu(a2*(N x) + e) ----------------
__global__ __launch_bounds__(256) void k3_out(const float* __restrict__ x,
                                              const float* __restrict__ ws,
                                              float* __restrict__ out){
  const int b = blockIdx.y, lc = blockIdx.x;
  const int t = threadIdx.x;
  const int w = __builtin_amdgcn_readfirstlane(t >> 6);
  const int lane = t & 63;
  const int l = lc*256 + 4*lane;
  const float* Np = ws + WS_N + b*4096 + w*1024;
  const float* xb = x + b*TC*TL + l;
  float4 acc[16];
  #pragma unroll
  for (int oo=0;oo<16;++oo){ acc[oo].x=0.f; acc[oo].y=0.f; acc[oo].z=0.f; acc[oo].w=0.f; }
  #pragma unroll 4
  for (int c=0;c<64;++c){
    const float4 xv = *(const float4*)(xb + c*TL);
    #pragma unroll
    for (int oo=0;oo<16;++oo){
      const float nv = Np[oo*64 + c];
      acc[oo].x = fmaf(nv, xv.x, acc[oo].x);
      acc[oo].y = fmaf(nv, xv.y, acc[oo].y);
      acc[oo].z = fmaf(nv, xv.z, acc[oo].z);
      acc[oo].w = fmaf(nv, xv.w, acc[oo].w);
    }
  }
  const float* a2p = ws + WS_A2E + w*16;
  const float* ep  = ws + WS_A2E + 64 + w*16;
  #pragma unroll
  for (int oo=0;oo<16;++oo){
    const float a2v = a2p[oo], ev = ep[oo];
    float4 r;
    r.x = fmaxf(fmaf(a2v, acc[oo].x, ev), 0.f);
    r.y = fmaxf(fmaf(a2v, acc[oo].y, ev), 0.f);
    r.z = fmaxf(fmaf(a2v, acc[oo].z, ev), 0.f);
    r.w = fmaxf(fmaf(a2v, acc[oo].w, ev), 0.f);
    *(float4*)(out + (b*TC + w*16 + oo)*TL + l) = r;
  }
}

extern "C" void kernel_launch(void* const* d_in, const int* in_sizes, int n_in,
                              void* d_out, int out_size, void* d_ws, size_t ws_size,
                              hipStream_t stream){
  const float* x  = (const float*)d_in[0];
  const float* wk = (const float*)d_in[1];
  const float* wq = (const float*)d_in[2];
  const float* wv = (const float*)d_in[3];
  const float* wc = (const float*)d_in[4];
  const float* g1 = (const float*)d_in[5];
  /* b1 (d_in[6]) provably cancels through BN2 mean-subtraction */
  const float* wl = (const float*)d_in[7];
  const float* g2 = (const float*)d_in[8];
  const float* b2 = (const float*)d_in[9];
  float* out = (float*)d_out;
  float* ws  = (float*)d_ws;

  k1_gram   <<<dim3(16,16), 256, 0, stream>>>(x, ws);
  k1b_reduce<<<16,          256, 0, stream>>>(ws);
  k2a_s1t   <<<dim3(4,16),  256, 0, stream>>>(wq, ws);
  k2b_attn_v1<<<dim3(16,16),256, 0, stream>>>(wk, wv, ws);
  k2d_mpart <<<dim3(4,16),  256, 0, stream>>>(wc, ws);
  k2e_stats1<<<16,          256, 0, stream>>>(ws);
  k2f_n_stats2<<<16,        256, 0, stream>>>(wl, g1, ws);
  k2g_final <<<1,            64, 0, stream>>>(g2, b2, ws);
  k3_out    <<<dim3(32,16), 256, 0, stream>>>(x, ws, out);
}

// Round 2
// 230.820 us; speedup vs baseline: 1.4610x; 1.4610x over previous
//
#include <hip/hip_runtime.h>
#include <math.h>

#define TB 16
#define TL 8192
#define TC 64
#define THC 256

constexpr float INV_BL = 1.0f / (16.0f * 8192.0f);
constexpr float EPSV = 1e-5f;
constexpr float INV_SQRT_H = 0.17677669529663687f; // 1/sqrt(32)

// workspace offsets (floats)
#define WS_G      0
#define WS_SX     65536
#define WS_STATS  66560   /* s1[64] s2[64] s1z[64] s2z[64] */
#define WS_M      66816
#define WS_N      132352
#define WS_A2E    197888  /* a2[64] e[64] */
#define WS_S1T    198016  /* [16][64][256] */
#define WS_GPART  722304  /* [16][16][4096]; reused by k2b as V1 partials [16][4][16384] */
#define WS_SXPART 1770880 /* [16][16][64]   */
#define WS_MPART  1787264 /* [4][16][4096]  */
// total 2049408 floats = 8.2 MB

__device__ __forceinline__ int swa(int l, int c){
  return l*64 + ((((c>>2) ^ (l&15))<<2) | (c&3));
}
__device__ __forceinline__ int gsw(int i, int j){
  return i*64 + ((((j>>2) ^ (i&15))<<2) | (j&3));
}

// ---------------- K1: Gram partials + row sums ----------------
__global__ __launch_bounds__(256) void k1_gram(const float* __restrict__ x,
                                               float* __restrict__ ws){
  __shared__ float xt[4096];
  __shared__ float gl[4096];
  const int b = blockIdx.y, chunk = blockIdx.x;
  const int t = threadIdx.x;
  const int cg = t>>4, m = t&15;
  const int grp = t>>6, ti = (t>>3)&7, tj = t&7;
  float acc[8][8];
  #pragma unroll
  for (int u=0;u<8;++u)
    #pragma unroll
    for (int v=0;v<8;++v) acc[u][v]=0.f;
  float sx[4] = {0.f,0.f,0.f,0.f};
  #pragma unroll
  for (int r=0;r<16;++r) gl[t+256*r]=0.f;
  const float* xb = x + b*TC*TL + chunk*512;
  for (int tile=0; tile<8; ++tile){
    const int l0 = tile*64;
    #pragma unroll
    for (int it=0; it<4; ++it){
      const int c = cg + 16*it;
      const float4 v = *(const float4*)(xb + c*TL + l0 + 4*m);
      sx[it] += v.x+v.y+v.z+v.w;
      const int l = 4*m;
      xt[swa(l+0,c)] = v.x;
      xt[swa(l+1,c)] = v.y;
      xt[swa(l+2,c)] = v.z;
      xt[swa(l+3,c)] = v.w;
    }
    __syncthreads();
    #pragma unroll 4
    for (int k=0;k<16;++k){
      const int l = grp*16 + k;
      const float4 xi0 = *(const float4*)&xt[swa(l, 8*ti)];
      const float4 xi1 = *(const float4*)&xt[swa(l, 8*ti+4)];
      const float4 xj0 = *(const float4*)&xt[swa(l, 8*tj)];
      const float4 xj1 = *(const float4*)&xt[swa(l, 8*tj+4)];
      const float xi[8] = {xi0.x,xi0.y,xi0.z,xi0.w, xi1.x,xi1.y,xi1.z,xi1.w};
      const float xj[8] = {xj0.x,xj0.y,xj0.z,xj0.w, xj1.x,xj1.y,xj1.z,xj1.w};
      #pragma unroll
      for (int u=0;u<8;++u)
        #pragma unroll
        for (int v=0;v<8;++v)
          acc[u][v] = fmaf(xi[u], xj[v], acc[u][v]);
    }
    __syncthreads();
  }
  #pragma unroll
  for (int u=0;u<8;++u)
    #pragma unroll
    for (int v=0;v<8;++v)
      atomicAdd(&gl[gsw(8*ti+u, 8*tj+v)], acc[u][v]);
  __syncthreads();
  float* Gp = ws + WS_GPART + (b*16 + chunk)*4096;
  #pragma unroll
  for (int r=0;r<16;++r){
    const int e = t + 256*r;
    Gp[e] = gl[gsw(e>>6, e&63)];
  }
  #pragma unroll
  for (int off=8; off>=1; off>>=1){
    sx[0] += __shfl_down(sx[0], off, 16);
    sx[1] += __shfl_down(sx[1], off, 16);
    sx[2] += __shfl_down(sx[2], off, 16);
    sx[3] += __shfl_down(sx[3], off, 16);
  }
  if (m==0){
    float* Sp = ws + WS_SXPART + (b*16+chunk)*64;
    Sp[cg]    = sx[0];
    Sp[cg+16] = sx[1];
    Sp[cg+32] = sx[2];
    Sp[cg+48] = sx[3];
  }
}

// ---------------- K1b: reduce partials, zero accumulators ----------------
__global__ __launch_bounds__(256) void k1b_reduce(float* __restrict__ ws){
  const int b = blockIdx.x, t = threadIdx.x;
  const float* Gp = ws + WS_GPART + b*16*4096;
  float* G = ws + WS_G + b*4096;
  #pragma unroll 4
  for (int r=0;r<16;++r){
    const int e = t + 256*r;
    float s = 0.f;
    #pragma unroll
    for (int ch=0;ch<16;++ch) s += Gp[ch*4096 + e];
    G[e] = s;
  }
  if (t < 64){
    const float* Sp = ws + WS_SXPART + b*16*64;
    float s = 0.f;
    #pragma unroll
    for (int ch=0; ch<16; ++ch) s += Sp[ch*64 + t];
    ws[WS_SX + b*64 + t] = s;
  }
  if (b==0) ws[WS_STATS + t] = 0.f;
}

// ---------------- K2A: S1^T = (wq G)^T ----------------
__global__ __launch_bounds__(256) void k2a_s1t(const float* __restrict__ wq,
                                               float* __restrict__ ws){
  __shared__ float Gt[64*68];
  const int b = blockIdx.y, iblk = blockIdx.x;
  const int t = threadIdx.x;
  const float* G = ws + WS_G + b*4096;
  #pragma unroll
  for (int r=0;r<4;++r){
    const int idx = r*1024 + t*4;
    *(float4*)&Gt[(idx>>6)*68 + (idx&63)] = *(const float4*)(G + idx);
  }
  __syncthreads();
  const int il = t>>2, cq = t&3;
  const int i = iblk*64 + il;
  const float* wqr = wq + i*64;
  float4 a0={0,0,0,0}, a1={0,0,0,0}, a2={0,0,0,0}, a3={0,0,0,0};
  #pragma unroll 8
  for (int k=0;k<64;++k){
    const float a = wqr[k];
    const float4 g0 = *(const float4*)&Gt[k*68 + cq*16 + 0];
    const float4 g1 = *(const float4*)&Gt[k*68 + cq*16 + 4];
    const float4 g2 = *(const float4*)&Gt[k*68 + cq*16 + 8];
    const float4 g3 = *(const float4*)&Gt[k*68 + cq*16 + 12];
    a0.x=fmaf(a,g0.x,a0.x); a0.y=fmaf(a,g0.y,a0.y); a0.z=fmaf(a,g0.z,a0.z); a0.w=fmaf(a,g0.w,a0.w);
    a1.x=fmaf(a,g1.x,a1.x); a1.y=fmaf(a,g1.y,a1.y); a1.z=fmaf(a,g1.z,a1.z); a1.w=fmaf(a,g1.w,a1.w);
    a2.x=fmaf(a,g2.x,a2.x); a2.y=fmaf(a,g2.y,a2.y); a2.z=fmaf(a,g2.z,a2.z); a2.w=fmaf(a,g2.w,a2.w);
    a3.x=fmaf(a,g3.x,a3.x); a3.y=fmaf(a,g3.y,a3.y); a3.z=fmaf(a,g3.z,a3.z); a3.w=fmaf(a,g3.w,a3.w);
  }
  float* S1T = ws + WS_S1T + b*16384;
  const int c0 = cq*16;
  S1T[(c0+ 0)*256 + i]=a0.x; S1T[(c0+ 1)*256 + i]=a0.y; S1T[(c0+ 2)*256 + i]=a0.z; S1T[(c0+ 3)*256 + i]=a0.w;
  S1T[(c0+ 4)*256 + i]=a1.x; S1T[(c0+ 5)*256 + i]=a1.y; S1T[(c0+ 6)*256 + i]=a1.z; S1T[(c0+ 7)*256 + i]=a1.w;
  S1T[(c0+ 8)*256 + i]=a2.x; S1T[(c0+ 9)*256 + i]=a2.y; S1T[(c0+10)*256 + i]=a2.z; S1T[(c0+11)*256 + i]=a2.w;
  S1T[(c0+12)*256 + i]=a3.x; S1T[(c0+13)*256 + i]=a3.y; S1T[(c0+14)*256 + i]=a3.z; S1T[(c0+15)*256 + i]=a3.w;
}

// ---------------- K2B: scores + column softmax + attn@wv -> V1 partials ----------------
// grid (4 jbg, 16 b); thread t owns row i=t; block owns 64 columns. No atomics.
__global__ __launch_bounds__(256) void k2b_attn_v1(const float* __restrict__ wk,
                                                   const float* __restrict__ wv,
                                                   float* __restrict__ ws){
  __shared__ float scl[256*65];   // scores staged for column stats (stride 65: conflict-free)
  __shared__ float wkl[64*64];    // [c][j] broadcast operand
  __shared__ float wvl[64*64];    // [j][c] broadcast operand
  __shared__ float partm[256];
  __shared__ float cstat[128];    // m[64], rinv[64]
  const int b = blockIdx.y, jbg = blockIdx.x;
  const int j0 = jbg*64;
  const int t = threadIdx.x;
  {
    const int j = t>>2, c0 = (t&3)*16;
    #pragma unroll
    for (int r=0;r<4;++r){
      const float4 v = *(const float4*)(wk + (j0+j)*64 + c0 + 4*r);
      wkl[(c0+4*r+0)*64 + j] = v.x;
      wkl[(c0+4*r+1)*64 + j] = v.y;
      wkl[(c0+4*r+2)*64 + j] = v.z;
      wkl[(c0+4*r+3)*64 + j] = v.w;
    }
    #pragma unroll
    for (int r=0;r<4;++r)
      *(float4*)&wvl[j*64 + c0 + 4*r] = *(const float4*)(wv + (j0+j)*64 + c0 + 4*r);
  }
  __syncthreads();
  // scores: row t x 64 columns, K=64 over channels
  const float* S1T = ws + WS_S1T + b*16384;
  {
    float sc[64];
    #pragma unroll
    for (int j=0;j<64;++j) sc[j]=0.f;
    #pragma unroll 4
    for (int c=0;c<64;++c){
      const float s1 = S1T[c*256 + t];
      #pragma unroll
      for (int j4=0;j4<16;++j4){
        const float4 w4 = *(const float4*)&wkl[c*64 + 4*j4];
        sc[4*j4+0] = fmaf(s1, w4.x, sc[4*j4+0]);
        sc[4*j4+1] = fmaf(s1, w4.y, sc[4*j4+1]);
        sc[4*j4+2] = fmaf(s1, w4.z, sc[4*j4+2]);
        sc[4*j4+3] = fmaf(s1, w4.w, sc[4*j4+3]);
      }
    }
    #pragma unroll
    for (int j=0;j<64;++j) scl[t*65 + j] = sc[j];
  }
  __syncthreads();
  // column stats: 4 partitions x 64 columns
  const int q = t>>6, jc = t&63;
  {
    float m = -3.0e38f;
    #pragma unroll 8
    for (int i=0;i<64;++i) m = fmaxf(m, scl[(q*64+i)*65 + jc]);
    partm[q*64+jc] = m;
  }
  __syncthreads();
  if (t<64)
    cstat[t] = fmaxf(fmaxf(partm[t], partm[64+t]), fmaxf(partm[128+t], partm[192+t]));
  __syncthreads();
  {
    const float mj = cstat[jc];
    float s = 0.f;
    #pragma unroll 8
    for (int i=0;i<64;++i) s += __expf(scl[(q*64+i)*65 + jc] - mj);
    partm[q*64+jc] = s;
  }
  __syncthreads();
  if (t<64)
    cstat[64+t] = 1.f / (partm[t]+partm[64+t]+partm[128+t]+partm[192+t]);
  __syncthreads();
  // PV: row t of attn (re-read from LDS) times wv tile
  float av[64];
  #pragma unroll
  for (int c=0;c<64;++c) av[c]=0.f;
  #pragma unroll 4
  for (int j=0;j<64;++j){
    const float p = __expf(scl[t*65 + j] - cstat[j]) * cstat[64+j];
    #pragma unroll
    for (int c4=0;c4<16;++c4){
      const float4 w4 = *(const float4*)&wvl[j*64 + 4*c4];
      av[4*c4+0] = fmaf(p, w4.x, av[4*c4+0]);
      av[4*c4+1] = fmaf(p, w4.y, av[4*c4+1]);
      av[4*c4+2] = fmaf(p, w4.z, av[4*c4+2]);
      av[4*c4+3] = fmaf(p, w4.w, av[4*c4+3]);
    }
  }
  float* Vp = ws + WS_GPART + (b*4 + jbg)*16384 + t*64;
  #pragma unroll
  for (int c4=0;c4<16;++c4){
    float4 v; v.x=av[4*c4]; v.y=av[4*c4+1]; v.z=av[4*c4+2]; v.w=av[4*c4+3];
    *(float4*)&Vp[4*c4] = v;
  }
}

// ---- shared 64x64 LDS GEMM helper: C[a][b] += sum_k A[k][a]*B[k][b] ----
__device__ __forceinline__ void gemm64_tile(const float* Al, const float* Bl,
                                            float* cds, int t){
  const int grp = t>>6, ta = (t>>3)&7, tb = t&7;
  float acc[8][8];
  #pragma unroll
  for (int u=0;u<8;++u)
    #pragma unroll
    for (int v=0;v<8;++v) acc[u][v]=0.f;
  #pragma unroll 4
  for (int kk=0;kk<16;++kk){
    const int k = grp*16 + kk;
    const float4 A0 = *(const float4*)&Al[k*68 + 8*ta];
    const float4 A1 = *(const float4*)&Al[k*68 + 8*ta + 4];
    const float4 B0 = *(const float4*)&Bl[k*68 + 8*tb];
    const float4 B1 = *(const float4*)&Bl[k*68 + 8*tb + 4];
    const float Aa[8] = {A0.x,A0.y,A0.z,A0.w,A1.x,A1.y,A1.z,A1.w};
    const float Bb[8] = {B0.x,B0.y,B0.z,B0.w,B1.x,B1.y,B1.z,B1.w};
    #pragma unroll
    for (int u=0;u<8;++u)
      #pragma unroll
      for (int v=0;v<8;++v) acc[u][v] = fmaf(Aa[u],Bb[v],acc[u][v]);
  }
  #pragma unroll
  for (int u=0;u<8;++u)
    #pragma unroll
    for (int v=0;v<8;++v)
      atomicAdd(&cds[gsw(8*ta+u, 8*tb+v)], acc[u][v]);
}

// ---------------- K2D: M partials = wc @ (sum of V1 partials) slice ----------------
__global__ __launch_bounds__(256) void k2d_mpart(const float* __restrict__ wc,
                                                 float* __restrict__ ws){
  __shared__ float wcT[64*68];
  __shared__ float V1l[64*68];
  __shared__ float ml[4096];
  const int b = blockIdx.y, ig = blockIdx.x;
  const int i0 = ig*64, t = threadIdx.x;
  #pragma unroll
  for (int r=0;r<16;++r) ml[t+256*r]=0.f;
  const float* V1p = ws + WS_GPART + b*4*16384 + i0*64;
  #pragma unroll
  for (int r=0;r<16;++r){
    const int e = t + 256*r;
    const float s = V1p[e] + V1p[16384+e] + V1p[2*16384+e] + V1p[3*16384+e];
    V1l[(e>>6)*68 + (e&63)] = s;
  }
  {
    const int o = t>>2;
    #pragma unroll
    for (int r=0;r<4;++r){
      const float4 v = *(const float4*)(wc + o*256 + i0 + (t&3)*16 + 4*r);
      const int ii = (t&3)*16 + 4*r;
      wcT[(ii+0)*68 + o] = v.x;
      wcT[(ii+1)*68 + o] = v.y;
      wcT[(ii+2)*68 + o] = v.z;
      wcT[(ii+3)*68 + o] = v.w;
    }
  }
  __syncthreads();
  gemm64_tile(wcT, V1l, ml, t);
  __syncthreads();
  float* Mp = ws + WS_MPART + (ig*16 + b)*4096;
  #pragma unroll
  for (int r=0;r<16;++r){
    const int e = t + 256*r;
    Mp[e] = ml[gsw(e>>6, e&63)] * INV_SQRT_H;
  }
}

// ---------------- K2E: M + BN1 stats ----------------
__global__ __launch_bounds__(256) void k2e_stats1(float* __restrict__ ws){
  __shared__ float Ml[64*68], MlT[64*68], Gt[64*68];
  __shared__ float tl[4096];
  __shared__ float Sxl[64];
  const int b = blockIdx.x, t = threadIdx.x;
  #pragma unroll
  for (int r=0;r<16;++r) tl[t+256*r]=0.f;
  #pragma unroll
  for (int r=0;r<16;++r){
    const int e = t + 256*r;
    float s = 0.f;
    #pragma unroll
    for (int ig=0; ig<4; ++ig) s += ws[WS_MPART + (ig*16+b)*4096 + e];
    const int o = e>>6, k = e&63;
    Ml[o*68+k] = s;
    MlT[k*68+o] = s;
    ws[WS_M + b*4096 + e] = s;
  }
  const float* G = ws + WS_G + b*4096;
  #pragma unroll
  for (int r=0;r<4;++r){
    const int idx = r*1024 + t*4;
    *(float4*)&Gt[(idx>>6)*68 + (idx&63)] = *(const float4*)(G + idx);
  }
  if (t<64) Sxl[t] = ws[WS_SX + b*64 + t];
  __syncthreads();
  if (t<64){
    float v = 0.f;
    #pragma unroll 8
    for (int k=0;k<64;++k) v += Ml[t*68+k]*Sxl[k];
    atomicAdd(&ws[WS_STATS + t], v);
  }
  gemm64_tile(MlT, Gt, tl, t);
  __syncthreads();
  {
    const int c = t>>2, jq = t&3;
    float v = 0.f;
    #pragma unroll
    for (int jj=0;jj<16;++jj){
      const int j = jq*16 + jj;
      v += tl[gsw(c, j)] * Ml[c*68 + j];
    }
    v += __shfl_xor(v, 2, 4);
    v += __shfl_xor(v, 1, 4);
    if (jq==0) atomicAdd(&ws[WS_STATS + 64 + c], v);
  }
}

// ---------------- K2F: N + BN2 stats ----------------
__global__ __launch_bounds__(256) void k2f_n_stats2(const float* __restrict__ wl,
                                                    const float* __restrict__ g1,
                                                    float* __restrict__ ws){
  __shared__ float Ml[64*68], Gt[64*68], wlT[64*68], Nl[64*68], NlT[64*68];
  __shared__ float nl[4096], tl[4096];
  __shared__ float Sxl[64], a1l[64];
  const int b = blockIdx.x, t = threadIdx.x;
  #pragma unroll
  for (int r=0;r<16;++r){ nl[t+256*r]=0.f; tl[t+256*r]=0.f; }
  if (t<64){
    const float mean1 = ws[WS_STATS+t]*INV_BL;
    const float var1 = ws[WS_STATS+64+t]*INV_BL - mean1*mean1;
    a1l[t] = g1[t]*rsqrtf(var1 + EPSV);
    Sxl[t] = ws[WS_SX + b*64 + t];
  }
  #pragma unroll
  for (int r=0;r<16;++r){
    const int e = t + 256*r;
    Ml[(e>>6)*68 + (e&63)] = ws[WS_M + b*4096 + e];
  }
  const float* G = ws + WS_G + b*4096;
  #pragma unroll
  for (int r=0;r<4;++r){
    const int idx = r*1024 + t*4;
    *(float4*)&Gt[(idx>>6)*68 + (idx&63)] = *(const float4*)(G + idx);
  }
  __syncthreads();
  {
    const int o = t>>2;
    #pragma unroll
    for (int r=0;r<4;++r){
      const float4 v = *(const float4*)(wl + o*64 + (t&3)*16 + 4*r);
      const int cc = (t&3)*16 + 4*r;
      wlT[(cc+0)*68 + o] = v.x*a1l[cc+0];
      wlT[(cc+1)*68 + o] = v.y*a1l[cc+1];
      wlT[(cc+2)*68 + o] = v.z*a1l[cc+2];
      wlT[(cc+3)*68 + o] = v.w*a1l[cc+3];
    }
  }
  __syncthreads();
  gemm64_tile(wlT, Ml, nl, t);
  __syncthreads();
  #pragma unroll
  for (int r=0;r<16;++r){
    const int e = t + 256*r;
    const int o = e>>6, k = e&63;
    const float nv = nl[gsw(o,k)] + wl[e];
    ws[WS_N + b*4096 + e] = nv;
    Nl[o*68+k] = nv;
    NlT[k*68+o] = nv;
  }
  __syncthreads();
  if (t<64){
    float v=0.f;
    #pragma unroll 8
    for (int k=0;k<64;++k) v += Nl[t*68+k]*Sxl[k];
    atomicAdd(&ws[WS_STATS + 128 + t], v);
  }
  gemm64_tile(NlT, Gt, tl, t);
  __syncthreads();
  {
    const int o = t>>2, jq = t&3;
    float v = 0.f;
    #pragma unroll
    for (int jj=0;jj<16;++jj){
      const int j = jq*16 + jj;
      v += tl[gsw(o, j)] * Nl[o*68 + j];
    }
    v += __shfl_xor(v, 2, 4);
    v += __shfl_xor(v, 1, 4);
    if (jq==0) atomicAdd(&ws[WS_STATS + 192 + o], v);
  }
}

// ---------------- K2G: a2, e ----------------
__global__ __launch_bounds__(64) void k2g_final(const float* __restrict__ g2,
                                                const float* __restrict__ b2,
                                                float* __restrict__ ws){
  const int o = threadIdx.x;
  const float mu = ws[WS_STATS+128+o]*INV_BL;
  const float var2 = ws[WS_STATS+192+o]*INV_BL - mu*mu;
  const float a2 = g2[o]*rsqrtf(var2 + EPSV);
  ws[WS_A2E+o] = a2;
  ws[WS_A2E+64+o] = b2[o] - a2*mu;
}

// ---------------- K3: out = relu(a2*(N x) + e) ----------------
__global__ __launch_bounds__(256) void k3_out(const float* __restrict__ x,
                                              const float* __restrict__ ws,
                                              float* __restrict__ out){
  const int b = blockIdx.y, lc = blockIdx.x;
  const int t = threadIdx.x;
  const int w = __builtin_amdgcn_readfirstlane(t >> 6);
  const int lane = t & 63;
  const int l = lc*256 + 4*lane;
  const float* Np = ws + WS_N + b*4096 + w*1024;
  const float* xb = x + b*TC*TL + l;
  float4 acc[16];
  #pragma unroll
  for (int oo=0;oo<16;++oo){ acc[oo].x=0.f; acc[oo].y=0.f; acc[oo].z=0.f; acc[oo].w=0.f; }
  #pragma unroll 4
  for (int c=0;c<64;++c){
    const float4 xv = *(const float4*)(xb + c*TL);
    #pragma unroll
    for (int oo=0;oo<16;++oo){
      const float nv = Np[oo*64 + c];
      acc[oo].x = fmaf(nv, xv.x, acc[oo].x);
      acc[oo].y = fmaf(nv, xv.y, acc[oo].y);
      acc[oo].z = fmaf(nv, xv.z, acc[oo].z);
      acc[oo].w = fmaf(nv, xv.w, acc[oo].w);
    }
  }
  const float* a2p = ws + WS_A2E + w*16;
  const float* ep  = ws + WS_A2E + 64 + w*16;
  #pragma unroll
  for (int oo=0;oo<16;++oo){
    const float a2v = a2p[oo], ev = ep[oo];
    float4 r;
    r.x = fmaxf(fmaf(a2v, acc[oo].x, ev), 0.f);
    r.y = fmaxf(fmaf(a2v, acc[oo].y, ev), 0.f);
    r.z = fmaxf(fmaf(a2v, acc[oo].z, ev), 0.f);
    r.w = fmaxf(fmaf(a2v, acc[oo].w, ev), 0.f);
    *(float4*)(out + (b*TC + w*16 + oo)*TL + l) = r;
  }
}

extern "C" void kernel_launch(void* const* d_in, const int* in_sizes, int n_in,
                              void* d_out, int out_size, void* d_ws, size_t ws_size,
                              hipStream_t stream){
  const float* x  = (const float*)d_in[0];
  const float* wk = (const float*)d_in[1];
  const float* wq = (const float*)d_in[2];
  const float* wv = (const float*)d_in[3];
  const float* wc = (const float*)d_in[4];
  const float* g1 = (const float*)d_in[5];
  /* b1 (d_in[6]) provably cancels through BN2 mean-subtraction */
  const float* wl = (const float*)d_in[7];
  const float* g2 = (const float*)d_in[8];
  const float* b2 = (const float*)d_in[9];
  float* out = (float*)d_out;
  float* ws  = (float*)d_ws;

  k1_gram   <<<dim3(16,16), 256, 0, stream>>>(x, ws);
  k1b_reduce<<<16,          256, 0, stream>>>(ws);
  k2a_s1t   <<<dim3(4,16),  256, 0, stream>>>(wq, ws);
  k2b_attn_v1<<<dim3(4,16), 256, 0, stream>>>(wk, wv, ws);
  k2d_mpart <<<dim3(4,16),  256, 0, stream>>>(wc, ws);
  k2e_stats1<<<16,          256, 0, stream>>>(ws);
  k2f_n_stats2<<<16,        256, 0, stream>>>(wl, g1, ws);
  k2g_final <<<1,            64, 0, stream>>>(g2, b2, ws);
  k3_out    <<<dim3(32,16), 256, 0, stream>>>(x, ws, out);
}

// Round 3
// 185.963 us; speedup vs baseline: 1.8134x; 1.2412x over previous
//
#include <hip/hip_runtime.h>
#include <math.h>

#define TB 16
#define TL 8192
#define TC 64

constexpr float INV_BL = 1.0f / (16.0f * 8192.0f);
constexpr float EPSV = 1e-5f;
constexpr float INV_SQRT_H = 0.17677669529663687f; // 1/sqrt(32)

// workspace offsets (floats)
#define WS_G      0        /* [16][64][64] */
#define WS_SX     65536    /* [16][64] */
#define WS_STATS  66560    /* s1[64] d1[64] s2[64] d2[64] */
#define WS_M      66816    /* [16][64][64] */
#define WS_N      132352   /* [16][64][64] */
#define WS_MPART  197888   /* [16][4][4096] -> ends 460032 */
#define WS_PV     460032   /* [16][4][16384] -> ends 1508608 (overlays GPART) */
#define WS_GPART  460032   /* K1 out: [16][16][4096] -> ends 1508608 */
#define WS_SXPART 1508608  /* [16][16][64] -> ends 1524992 */
// total 1524992 floats = 6.1 MB

__device__ __forceinline__ int swa(int l, int c){
  return l*64 + ((((c>>2) ^ (l&15))<<2) | (c&3));
}
__device__ __forceinline__ int gsw(int i, int j){
  return i*64 + ((((j>>2) ^ (i&15))<<2) | (j&3));
}

// ---------------- K1: Gram partials + row sums (unchanged) ----------------
__global__ __launch_bounds__(256) void k1_gram(const float* __restrict__ x,
                                               float* __restrict__ ws){
  __shared__ float xt[4096];
  __shared__ float gl[4096];
  const int b = blockIdx.y, chunk = blockIdx.x;
  const int t = threadIdx.x;
  const int cg = t>>4, m = t&15;
  const int grp = t>>6, ti = (t>>3)&7, tj = t&7;
  float acc[8][8];
  #pragma unroll
  for (int u=0;u<8;++u)
    #pragma unroll
    for (int v=0;v<8;++v) acc[u][v]=0.f;
  float sx[4] = {0.f,0.f,0.f,0.f};
  #pragma unroll
  for (int r=0;r<16;++r) gl[t+256*r]=0.f;
  const float* xb = x + b*TC*TL + chunk*512;
  for (int tile=0; tile<8; ++tile){
    const int l0 = tile*64;
    #pragma unroll
    for (int it=0; it<4; ++it){
      const int c = cg + 16*it;
      const float4 v = *(const float4*)(xb + c*TL + l0 + 4*m);
      sx[it] += v.x+v.y+v.z+v.w;
      const int l = 4*m;
      xt[swa(l+0,c)] = v.x;
      xt[swa(l+1,c)] = v.y;
      xt[swa(l+2,c)] = v.z;
      xt[swa(l+3,c)] = v.w;
    }
    __syncthreads();
    #pragma unroll 4
    for (int k=0;k<16;++k){
      const int l = grp*16 + k;
      const float4 xi0 = *(const float4*)&xt[swa(l, 8*ti)];
      const float4 xi1 = *(const float4*)&xt[swa(l, 8*ti+4)];
      const float4 xj0 = *(const float4*)&xt[swa(l, 8*tj)];
      const float4 xj1 = *(const float4*)&xt[swa(l, 8*tj+4)];
      const float xi[8] = {xi0.x,xi0.y,xi0.z,xi0.w, xi1.x,xi1.y,xi1.z,xi1.w};
      const float xj[8] = {xj0.x,xj0.y,xj0.z,xj0.w, xj1.x,xj1.y,xj1.z,xj1.w};
      #pragma unroll
      for (int u=0;u<8;++u)
        #pragma unroll
        for (int v=0;v<8;++v)
          acc[u][v] = fmaf(xi[u], xj[v], acc[u][v]);
    }
    __syncthreads();
  }
  #pragma unroll
  for (int u=0;u<8;++u)
    #pragma unroll
    for (int v=0;v<8;++v)
      atomicAdd(&gl[gsw(8*ti+u, 8*tj+v)], acc[u][v]);
  __syncthreads();
  float* Gp = ws + WS_GPART + (b*16 + chunk)*4096;
  #pragma unroll
  for (int r=0;r<16;++r){
    const int e = t + 256*r;
    Gp[e] = gl[gsw(e>>6, e&63)];
  }
  #pragma unroll
  for (int off=8; off>=1; off>>=1){
    sx[0] += __shfl_down(sx[0], off, 16);
    sx[1] += __shfl_down(sx[1], off, 16);
    sx[2] += __shfl_down(sx[2], off, 16);
    sx[3] += __shfl_down(sx[3], off, 16);
  }
  if (m==0){
    float* Sp = ws + WS_SXPART + (b*16+chunk)*64;
    Sp[cg]    = sx[0];
    Sp[cg+16] = sx[1];
    Sp[cg+32] = sx[2];
    Sp[cg+48] = sx[3];
  }
}

// ---------------- KA: reduce G/Sx partials, zero stats ----------------
__global__ __launch_bounds__(256) void ka_reduce(float* __restrict__ ws){
  const int b = blockIdx.y, ig = blockIdx.x;
  const int t = threadIdx.x;
  const int base = ig*1024;
  float s[4] = {0.f,0.f,0.f,0.f};
  const float* Gp = ws + WS_GPART + b*16*4096 + base;
  #pragma unroll 4
  for (int ch=0; ch<16; ++ch){
    #pragma unroll
    for (int r=0;r<4;++r) s[r] += Gp[ch*4096 + t + 256*r];
  }
  #pragma unroll
  for (int r=0;r<4;++r) ws[WS_G + b*4096 + base + t + 256*r] = s[r];
  if (ig==0){
    if (t<64){
      float sv = 0.f;
      #pragma unroll 4
      for (int ch=0; ch<16; ++ch) sv += ws[WS_SXPART + (b*16+ch)*64 + t];
      ws[WS_SX + b*64 + t] = sv;
    }
    if (b==0) ws[WS_STATS + t] = 0.f;
  }
}

// ---------------- KB: attention (col-per-lane softmax) -> PV partials ----------------
// grid (4 jp, 16 b). Block owns cols [jp*64, +64), all 256 rows.
__global__ __launch_bounds__(256) void kb_attn(const float* __restrict__ wk,
                                               const float* __restrict__ wv,
                                               const float* __restrict__ wq,
                                               float* __restrict__ ws){
  __shared__ float lds[12928];
  float* wkj = lds;           // [64][68] stride 68 -> 4352 (dead after T)
  float* Tl  = lds + 4352;    // [64][64] -> 8448 (dead after scores)
  float* Pl  = lds;           // [64][65] chunk P, overlays wkj/Tl
  float* wvl = lds + 8448;    // [64][64] -> 12544
  float* pstat = lds + 12544; // [256]
  float* fstat = lds + 12800; // m[64], rinv[64]
  const int b = blockIdx.y, jp = blockIdx.x;
  const int j0 = jp*64;
  const int t = threadIdx.x;
  {
    const int j = t>>2, c0 = (t&3)*16;
    #pragma unroll
    for (int r=0;r<4;++r){
      *(float4*)&wkj[j*68 + c0 + 4*r] = *(const float4*)(wk + (j0+j)*64 + c0 + 4*r);
      *(float4*)&wvl[j*64 + c0 + 4*r] = *(const float4*)(wv + (j0+j)*64 + c0 + 4*r);
    }
  }
  __syncthreads();
  // T[k][j] = sum_c G[k][c] * wk[j][c]
  {
    const int k = t>>2, jq = t&3;
    const float* gr = ws + WS_G + b*4096 + k*64;
    float acc[16];
    #pragma unroll
    for (int jj=0;jj<16;++jj) acc[jj]=0.f;
    #pragma unroll 4
    for (int c=0;c<64;++c){
      const float g = gr[c];
      #pragma unroll
      for (int jj=0;jj<16;++jj)
        acc[jj] = fmaf(g, wkj[(jq*16+jj)*68 + c], acc[jj]);
    }
    #pragma unroll
    for (int jj=0;jj<16;++jj) Tl[k*64 + jq*16 + jj] = acc[jj];
  }
  __syncthreads();
  // scores: wave iq owns row-slice [iq*64,+64), lane j owns column j0+j
  const int iq = __builtin_amdgcn_readfirstlane(t>>6);
  const int j  = t&63;
  const float* wqp = wq + iq*4096;
  float sc[64];
  #pragma unroll
  for (int ii=0;ii<64;++ii) sc[ii]=0.f;
  #pragma unroll 2
  for (int k=0;k<64;++k){
    const float tv = Tl[k*64 + j];
    #pragma unroll
    for (int ii=0;ii<64;++ii)
      sc[ii] = fmaf(wqp[ii*64+k], tv, sc[ii]);
  }
  // column softmax: stats are thread-local scalars after 4-way reduce
  float mx = -3.0e38f;
  #pragma unroll
  for (int ii=0;ii<64;++ii) mx = fmaxf(mx, sc[ii]);
  pstat[iq*64 + j] = mx;
  __syncthreads();
  if (t<64) fstat[t] = fmaxf(fmaxf(pstat[t],pstat[64+t]),fmaxf(pstat[128+t],pstat[192+t]));
  __syncthreads();
  const float mj = fstat[j];
  float sm = 0.f;
  #pragma unroll
  for (int ii=0;ii<64;++ii){ sc[ii] = __expf(sc[ii]-mj); sm += sc[ii]; }
  pstat[iq*64 + j] = sm;
  __syncthreads();
  if (t<64) fstat[64+t] = 1.f/(pstat[t]+pstat[64+t]+pstat[128+t]+pstat[192+t]);
  __syncthreads();
  const float rj = fstat[64+j];
  // PV in 4 row-chunks: wave ch publishes its P slice, all waves consume
  const int ro = t>>2, cq = t&3;
  float* Vp = ws + WS_PV + (b*4 + jp)*16384;
  for (int ch=0; ch<4; ++ch){
    __syncthreads();
    if (iq == ch){
      #pragma unroll
      for (int ii=0;ii<64;++ii) Pl[ii*65 + j] = sc[ii]*rj;
    }
    __syncthreads();
    float acc[16];
    #pragma unroll
    for (int cc=0;cc<16;++cc) acc[cc]=0.f;
    #pragma unroll 4
    for (int jj=0;jj<64;++jj){
      const float p = Pl[ro*65 + jj];
      #pragma unroll
      for (int g=0;g<4;++g){
        const float4 w4 = *(const float4*)&wvl[jj*64 + cq*16 + 4*g];
        acc[4*g+0] = fmaf(p, w4.x, acc[4*g+0]);
        acc[4*g+1] = fmaf(p, w4.y, acc[4*g+1]);
        acc[4*g+2] = fmaf(p, w4.z, acc[4*g+2]);
        acc[4*g+3] = fmaf(p, w4.w, acc[4*g+3]);
      }
    }
    #pragma unroll
    for (int g=0;g<4;++g){
      float4 v; v.x=acc[4*g]; v.y=acc[4*g+1]; v.z=acc[4*g+2]; v.w=acc[4*g+3];
      *(float4*)&Vp[(ch*64+ro)*64 + cq*16 + 4*g] = v;
    }
  }
}

// ---------------- KC: V1 reduce + M K-partials ----------------
// grid (4 kq, 16 b): block handles V1 rows i in [kq*64,+64)
__global__ __launch_bounds__(256) void kc_mpart(const float* __restrict__ wc,
                                                float* __restrict__ ws){
  __shared__ float V1s[64*65];
  __shared__ float wcs[64*65];
  const int b = blockIdx.y, kq = blockIdx.x;
  const int t = threadIdx.x;
  const float* Vp = ws + WS_PV + b*4*16384 + kq*4096;
  #pragma unroll 4
  for (int r=0;r<16;++r){
    const int e = t + 256*r;
    const float s = Vp[e] + Vp[16384+e] + Vp[2*16384+e] + Vp[3*16384+e];
    V1s[(e>>6)*65 + (e&63)] = s;
  }
  #pragma unroll 4
  for (int r=0;r<16;++r){
    const int e = t + 256*r;
    wcs[(e>>6)*65 + (e&63)] = wc[(e>>6)*256 + kq*64 + (e&63)];
  }
  __syncthreads();
  const int o = t>>2, cq = t&3;
  float acc[16];
  #pragma unroll
  for (int cc=0;cc<16;++cc) acc[cc]=0.f;
  #pragma unroll 4
  for (int i=0;i<64;++i){
    const float w = wcs[o*65 + i];
    #pragma unroll
    for (int g=0;g<4;++g){
      const float4 v4 = *(const float4*)&V1s[i*65 + cq*16 + 4*g];
      acc[4*g+0] = fmaf(w, v4.x, acc[4*g+0]);
      acc[4*g+1] = fmaf(w, v4.y, acc[4*g+1]);
      acc[4*g+2] = fmaf(w, v4.z, acc[4*g+2]);
      acc[4*g+3] = fmaf(w, v4.w, acc[4*g+3]);
    }
  }
  float* Mp = ws + WS_MPART + (b*4 + kq)*4096;
  #pragma unroll
  for (int g=0;g<4;++g){
    float4 v;
    v.x=acc[4*g]*INV_SQRT_H; v.y=acc[4*g+1]*INV_SQRT_H;
    v.z=acc[4*g+2]*INV_SQRT_H; v.w=acc[4*g+3]*INV_SQRT_H;
    *(float4*)&Mp[o*64 + cq*16 + 4*g] = v;
  }
}

// ---------------- KD: M rows + BN1 stats partials ----------------
// grid (4 oq, 16 b): block owns M rows [oq*16,+16)
__global__ __launch_bounds__(256) void kd_stats1(float* __restrict__ ws){
  __shared__ float Msub[16*65];
  __shared__ float Gl[64*67];
  __shared__ float Sxl[64];
  const int b = blockIdx.y, oq = blockIdx.x;
  const int t = threadIdx.x;
  const float* Mp = ws + WS_MPART + b*4*4096 + oq*1024;
  #pragma unroll
  for (int r=0;r<4;++r){
    const int e = t + 256*r;
    const float s = Mp[e] + Mp[4096+e] + Mp[2*4096+e] + Mp[3*4096+e];
    ws[WS_M + b*4096 + oq*1024 + e] = s;
    Msub[(e>>6)*65 + (e&63)] = s;
  }
  #pragma unroll 4
  for (int r=0;r<16;++r){
    const int e = t + 256*r;
    Gl[(e>>6)*67 + (e&63)] = ws[WS_G + b*4096 + e];
  }
  if (t<64) Sxl[t] = ws[WS_SX + b*64 + t];
  __syncthreads();
  const int o = t>>4, q = t&15;
  float d = 0.f;
  #pragma unroll
  for (int kk=0;kk<4;++kk){
    const int k = q*4+kk;
    float s = 0.f;
    #pragma unroll 4
    for (int c=0;c<64;++c) s = fmaf(Gl[k*67+c], Msub[o*65+c], s);
    d = fmaf(Msub[o*65+k], s, d);
  }
  d += __shfl_xor(d, 1, 16);
  d += __shfl_xor(d, 2, 16);
  d += __shfl_xor(d, 4, 16);
  d += __shfl_xor(d, 8, 16);
  if (q==0){
    float s1 = 0.f;
    #pragma unroll 4
    for (int c=0;c<64;++c) s1 = fmaf(Msub[o*65+c], Sxl[c], s1);
    atomicAdd(&ws[WS_STATS + oq*16 + o], s1);
    atomicAdd(&ws[WS_STATS + 64 + oq*16 + o], d);
  }
}

// ---------------- KE: N rows + BN2 stats partials ----------------
// grid (4 oq, 16 b)
__global__ __launch_bounds__(256) void ke_n_stats2(const float* __restrict__ wl,
                                                   const float* __restrict__ g1,
                                                   float* __restrict__ ws){
  __shared__ float Ml[64*65];
  __shared__ float Gl[64*67];
  __shared__ float wls[16*65];
  __shared__ float Nsub[16*65];
  __shared__ float Sxl[64], a1l[64];
  const int b = blockIdx.y, oq = blockIdx.x;
  const int t = threadIdx.x;
  if (t<64){
    const float mean1 = ws[WS_STATS+t]*INV_BL;
    const float var1 = ws[WS_STATS+64+t]*INV_BL - mean1*mean1;
    a1l[t] = g1[t]*rsqrtf(var1 + EPSV);
    Sxl[t] = ws[WS_SX + b*64 + t];
  }
  #pragma unroll 4
  for (int r=0;r<16;++r){
    const int e = t + 256*r;
    Ml[(e>>6)*65 + (e&63)] = ws[WS_M + b*4096 + e];
    Gl[(e>>6)*67 + (e&63)] = ws[WS_G + b*4096 + e];
  }
  __syncthreads();
  #pragma unroll
  for (int r=0;r<4;++r){
    const int e = t + 256*r;
    wls[(e>>6)*65 + (e&63)] = wl[(oq*16 + (e>>6))*64 + (e&63)] * a1l[e&63];
  }
  __syncthreads();
  const int o = t>>4, q = t&15;
  const int row = oq*16 + o;
  {
    float acc[4];
    #pragma unroll
    for (int cc=0;cc<4;++cc) acc[cc]=0.f;
    #pragma unroll 4
    for (int k=0;k<64;++k){
      const float w = wls[o*65 + k];
      #pragma unroll
      for (int cc=0;cc<4;++cc)
        acc[cc] = fmaf(w, Ml[k*65 + q*4 + cc], acc[cc]);
    }
    #pragma unroll
    for (int cc=0;cc<4;++cc){
      const float nv = acc[cc] + wl[row*64 + q*4 + cc];
      ws[WS_N + b*4096 + o*64 + oq*1024 + q*4 + cc] = nv;
      Nsub[o*65 + q*4 + cc] = nv;
    }
  }
  __syncthreads();
  float d = 0.f;
  #pragma unroll
  for (int kk=0;kk<4;++kk){
    const int k = q*4+kk;
    float s = 0.f;
    #pragma unroll 4
    for (int c=0;c<64;++c) s = fmaf(Gl[k*67+c], Nsub[o*65+c], s);
    d = fmaf(Nsub[o*65+k], s, d);
  }
  d += __shfl_xor(d, 1, 16);
  d += __shfl_xor(d, 2, 16);
  d += __shfl_xor(d, 4, 16);
  d += __shfl_xor(d, 8, 16);
  if (q==0){
    float s2 = 0.f;
    #pragma unroll 4
    for (int c=0;c<64;++c) s2 = fmaf(Nsub[o*65+c], Sxl[c], s2);
    atomicAdd(&ws[WS_STATS + 128 + row], s2);
    atomicAdd(&ws[WS_STATS + 192 + row], d);
  }
}

// ---------------- K3: out = relu(a2*(N x) + e) ----------------
__global__ __launch_bounds__(256) void k3_out(const float* __restrict__ x,
                                              const float* __restrict__ g2,
                                              const float* __restrict__ b2,
                                              const float* __restrict__ ws,
                                              float* __restrict__ out){
  __shared__ float a2l[64], el[64];
  const int b = blockIdx.y, lc = blockIdx.x;
  const int t = threadIdx.x;
  if (t<64){
    const float mu = ws[WS_STATS+128+t]*INV_BL;
    const float var2 = ws[WS_STATS+192+t]*INV_BL - mu*mu;
    const float a2 = g2[t]*rsqrtf(var2 + EPSV);
    a2l[t] = a2;
    el[t] = b2[t] - a2*mu;
  }
  __syncthreads();
  const int w = __builtin_amdgcn_readfirstlane(t >> 6);
  const int lane = t & 63;
  const int l = lc*256 + 4*lane;
  const float* Np = ws + WS_N + b*4096 + w*1024;
  const float* xb = x + b*TC*TL + l;
  float4 acc[16];
  #pragma unroll
  for (int oo=0;oo<16;++oo){ acc[oo].x=0.f; acc[oo].y=0.f; acc[oo].z=0.f; acc[oo].w=0.f; }
  #pragma unroll 4
  for (int c=0;c<64;++c){
    const float4 xv = *(const float4*)(xb + c*TL);
    #pragma unroll
    for (int oo=0;oo<16;++oo){
      const float nv = Np[oo*64 + c];
      acc[oo].x = fmaf(nv, xv.x, acc[oo].x);
      acc[oo].y = fmaf(nv, xv.y, acc[oo].y);
      acc[oo].z = fmaf(nv, xv.z, acc[oo].z);
      acc[oo].w = fmaf(nv, xv.w, acc[oo].w);
    }
  }
  #pragma unroll
  for (int oo=0;oo<16;++oo){
    const float a2v = a2l[w*16+oo], ev = el[w*16+oo];
    float4 r;
    r.x = fmaxf(fmaf(a2v, acc[oo].x, ev), 0.f);
    r.y = fmaxf(fmaf(a2v, acc[oo].y, ev), 0.f);
    r.z = fmaxf(fmaf(a2v, acc[oo].z, ev), 0.f);
    r.w = fmaxf(fmaf(a2v, acc[oo].w, ev), 0.f);
    *(float4*)(out + (b*TC + w*16 + oo)*TL + l) = r;
  }
}

extern "C" void kernel_launch(void* const* d_in, const int* in_sizes, int n_in,
                              void* d_out, int out_size, void* d_ws, size_t ws_size,
                              hipStream_t stream){
  const float* x  = (const float*)d_in[0];
  const float* wk = (const float*)d_in[1];
  const float* wq = (const float*)d_in[2];
  const float* wv = (const float*)d_in[3];
  const float* wc = (const float*)d_in[4];
  const float* g1 = (const float*)d_in[5];
  /* b1 (d_in[6]) provably cancels through BN2 mean-subtraction */
  const float* wl = (const float*)d_in[7];
  const float* g2 = (const float*)d_in[8];
  const float* b2 = (const float*)d_in[9];
  float* out = (float*)d_out;
  float* ws  = (float*)d_ws;

  k1_gram    <<<dim3(16,16), 256, 0, stream>>>(x, ws);
  ka_reduce  <<<dim3(4,16),  256, 0, stream>>>(ws);
  kb_attn    <<<dim3(4,16),  256, 0, stream>>>(wk, wv, wq, ws);
  kc_mpart   <<<dim3(4,16),  256, 0, stream>>>(wc, ws);
  kd_stats1  <<<dim3(4,16),  256, 0, stream>>>(ws);
  ke_n_stats2<<<dim3(4,16),  256, 0, stream>>>(wl, g1, ws);
  k3_out     <<<dim3(32,16), 256, 0, stream>>>(x, g2, b2, ws, out);
}

// Round 4
// 150.356 us; speedup vs baseline: 2.2428x; 1.2368x over previous
//
#include <hip/hip_runtime.h>
#include <math.h>

#define TB 16
#define TL 8192
#define TC 64

constexpr float INV_BL = 1.0f / (16.0f * 8192.0f);
constexpr float EPSV = 1e-5f;
constexpr float INV_SQRT_H = 0.17677669529663687f; // 1/sqrt(32)

// workspace offsets (floats)
#define WS_G      0        /* [16][64][64] */
#define WS_SX     65536    /* [16][64] */
#define WS_STATS  66560    /* s1[64] d1[64] s2[64] d2[64] */
#define WS_M      66816    /* [16][64][64] */
#define WS_N      132352   /* [16][64][64] */
#define WS_MPART  197888   /* [16][4][4096] -> ends 460032 */
#define WS_PT     460032   /* attn^T [16][256][256] -> ends 1508608 (overlays GPART) */
#define WS_GPART  460032   /* K1 out: [16][16][4096] -> ends 1508608 */
#define WS_SXPART 1508608  /* [16][16][64] -> ends 1524992 */
#define WS_V1     1524992  /* [16][256][64] -> ends 1787136 */
#define WS_S1T    1787136  /* [16][64][256] -> ends 2049280 */
// total 2049280 floats = 8.2 MB (same budget as R1)

__device__ __forceinline__ int swa(int l, int c){
  return l*64 + ((((c>>2) ^ (l&15))<<2) | (c&3));
}
__device__ __forceinline__ int gsw(int i, int j){
  return i*64 + ((((j>>2) ^ (i&15))<<2) | (j&3));
}

// ---------------- K1: Gram partials + row sums (unchanged) ----------------
__global__ __launch_bounds__(256) void k1_gram(const float* __restrict__ x,
                                               float* __restrict__ ws){
  __shared__ float xt[4096];
  __shared__ float gl[4096];
  const int b = blockIdx.y, chunk = blockIdx.x;
  const int t = threadIdx.x;
  const int cg = t>>4, m = t&15;
  const int grp = t>>6, ti = (t>>3)&7, tj = t&7;
  float acc[8][8];
  #pragma unroll
  for (int u=0;u<8;++u)
    #pragma unroll
    for (int v=0;v<8;++v) acc[u][v]=0.f;
  float sx[4] = {0.f,0.f,0.f,0.f};
  #pragma unroll
  for (int r=0;r<16;++r) gl[t+256*r]=0.f;
  const float* xb = x + b*TC*TL + chunk*512;
  for (int tile=0; tile<8; ++tile){
    const int l0 = tile*64;
    #pragma unroll
    for (int it=0; it<4; ++it){
      const int c = cg + 16*it;
      const float4 v = *(const float4*)(xb + c*TL + l0 + 4*m);
      sx[it] += v.x+v.y+v.z+v.w;
      const int l = 4*m;
      xt[swa(l+0,c)] = v.x;
      xt[swa(l+1,c)] = v.y;
      xt[swa(l+2,c)] = v.z;
      xt[swa(l+3,c)] = v.w;
    }
    __syncthreads();
    #pragma unroll 4
    for (int k=0;k<16;++k){
      const int l = grp*16 + k;
      const float4 xi0 = *(const float4*)&xt[swa(l, 8*ti)];
      const float4 xi1 = *(const float4*)&xt[swa(l, 8*ti+4)];
      const float4 xj0 = *(const float4*)&xt[swa(l, 8*tj)];
      const float4 xj1 = *(const float4*)&xt[swa(l, 8*tj+4)];
      const float xi[8] = {xi0.x,xi0.y,xi0.z,xi0.w, xi1.x,xi1.y,xi1.z,xi1.w};
      const float xj[8] = {xj0.x,xj0.y,xj0.z,xj0.w, xj1.x,xj1.y,xj1.z,xj1.w};
      #pragma unroll
      for (int u=0;u<8;++u)
        #pragma unroll
        for (int v=0;v<8;++v)
          acc[u][v] = fmaf(xi[u], xj[v], acc[u][v]);
    }
    __syncthreads();
  }
  #pragma unroll
  for (int u=0;u<8;++u)
    #pragma unroll
    for (int v=0;v<8;++v)
      atomicAdd(&gl[gsw(8*ti+u, 8*tj+v)], acc[u][v]);
  __syncthreads();
  float* Gp = ws + WS_GPART + (b*16 + chunk)*4096;
  #pragma unroll
  for (int r=0;r<16;++r){
    const int e = t + 256*r;
    Gp[e] = gl[gsw(e>>6, e&63)];
  }
  #pragma unroll
  for (int off=8; off>=1; off>>=1){
    sx[0] += __shfl_down(sx[0], off, 16);
    sx[1] += __shfl_down(sx[1], off, 16);
    sx[2] += __shfl_down(sx[2], off, 16);
    sx[3] += __shfl_down(sx[3], off, 16);
  }
  if (m==0){
    float* Sp = ws + WS_SXPART + (b*16+chunk)*64;
    Sp[cg]    = sx[0];
    Sp[cg+16] = sx[1];
    Sp[cg+32] = sx[2];
    Sp[cg+48] = sx[3];
  }
}

// ---------------- KA: reduce G/Sx partials, zero stats ----------------
__global__ __launch_bounds__(256) void ka_reduce(float* __restrict__ ws){
  const int b = blockIdx.y, ig = blockIdx.x;
  const int t = threadIdx.x;
  const int base = ig*1024;
  float s[4] = {0.f,0.f,0.f,0.f};
  const float* Gp = ws + WS_GPART + b*16*4096 + base;
  #pragma unroll 4
  for (int ch=0; ch<16; ++ch){
    #pragma unroll
    for (int r=0;r<4;++r) s[r] += Gp[ch*4096 + t + 256*r];
  }
  #pragma unroll
  for (int r=0;r<4;++r) ws[WS_G + b*4096 + base + t + 256*r] = s[r];
  if (ig==0){
    if (t<64){
      float sv = 0.f;
      #pragma unroll 4
      for (int ch=0; ch<16; ++ch) sv += ws[WS_SXPART + (b*16+ch)*64 + t];
      ws[WS_SX + b*64 + t] = sv;
    }
    if (b==0) ws[WS_STATS + t] = 0.f;
  }
}

// ---------------- KA2: S1^T = (wq G)^T  (R1-proven structure) ----------------
__global__ __launch_bounds__(256) void ka2_s1t(const float* __restrict__ wq,
                                               float* __restrict__ ws){
  __shared__ float Gt[64*68];
  const int b = blockIdx.y, iblk = blockIdx.x;
  const int t = threadIdx.x;
  const float* G = ws + WS_G + b*4096;
  #pragma unroll
  for (int r=0;r<4;++r){
    const int idx = r*1024 + t*4;
    *(float4*)&Gt[(idx>>6)*68 + (idx&63)] = *(const float4*)(G + idx);
  }
  __syncthreads();
  const int il = t>>2, cq = t&3;
  const int i = iblk*64 + il;
  const float* wqr = wq + i*64;
  float4 a0={0,0,0,0}, a1={0,0,0,0}, a2={0,0,0,0}, a3={0,0,0,0};
  #pragma unroll 8
  for (int k=0;k<64;++k){
    const float a = wqr[k];
    const float4 g0 = *(const float4*)&Gt[k*68 + cq*16 + 0];
    const float4 g1 = *(const float4*)&Gt[k*68 + cq*16 + 4];
    const float4 g2 = *(const float4*)&Gt[k*68 + cq*16 + 8];
    const float4 g3 = *(const float4*)&Gt[k*68 + cq*16 + 12];
    a0.x=fmaf(a,g0.x,a0.x); a0.y=fmaf(a,g0.y,a0.y); a0.z=fmaf(a,g0.z,a0.z); a0.w=fmaf(a,g0.w,a0.w);
    a1.x=fmaf(a,g1.x,a1.x); a1.y=fmaf(a,g1.y,a1.y); a1.z=fmaf(a,g1.z,a1.z); a1.w=fmaf(a,g1.w,a1.w);
    a2.x=fmaf(a,g2.x,a2.x); a2.y=fmaf(a,g2.y,a2.y); a2.z=fmaf(a,g2.z,a2.z); a2.w=fmaf(a,g2.w,a2.w);
    a3.x=fmaf(a,g3.x,a3.x); a3.y=fmaf(a,g3.y,a3.y); a3.z=fmaf(a,g3.z,a3.z); a3.w=fmaf(a,g3.w,a3.w);
  }
  float* S1T = ws + WS_S1T + b*16384;
  const int c0 = cq*16;
  S1T[(c0+ 0)*256 + i]=a0.x; S1T[(c0+ 1)*256 + i]=a0.y; S1T[(c0+ 2)*256 + i]=a0.z; S1T[(c0+ 3)*256 + i]=a0.w;
  S1T[(c0+ 4)*256 + i]=a1.x; S1T[(c0+ 5)*256 + i]=a1.y; S1T[(c0+ 6)*256 + i]=a1.z; S1T[(c0+ 7)*256 + i]=a1.w;
  S1T[(c0+ 8)*256 + i]=a2.x; S1T[(c0+ 9)*256 + i]=a2.y; S1T[(c0+10)*256 + i]=a2.z; S1T[(c0+11)*256 + i]=a2.w;
  S1T[(c0+12)*256 + i]=a3.x; S1T[(c0+13)*256 + i]=a3.y; S1T[(c0+14)*256 + i]=a3.z; S1T[(c0+15)*256 + i]=a3.w;
}

// ---------------- KB1: scores + column softmax -> P^T (global) ----------------
// grid (16 jp, 16 b): block owns 16 cols, thread t = row. sc[16] only.
__global__ __launch_bounds__(256) void kb1_scores(const float* __restrict__ wk,
                                                  float* __restrict__ ws){
  __shared__ float scl[256*17];
  __shared__ float pstat[256];
  __shared__ float fstat[32];
  const int b = blockIdx.y, jp = blockIdx.x;
  const int j0 = jp*16;
  const int t = threadIdx.x;
  const float* S1Tb = ws + WS_S1T + b*16384;
  float sc[16];
  #pragma unroll
  for (int jj=0;jj<16;++jj) sc[jj]=0.f;
  #pragma unroll 2
  for (int k=0;k<64;++k){
    const float s1 = S1Tb[k*256 + t];          // coalesced
    const float* wkr = wk + j0*64 + k;         // uniform -> s_load
    #pragma unroll
    for (int jj=0;jj<16;++jj)
      sc[jj] = fmaf(wkr[jj*64], s1, sc[jj]);
  }
  #pragma unroll
  for (int jj=0;jj<16;++jj) scl[t*17+jj] = sc[jj];
  __syncthreads();
  const int col = t&15, ig = t>>4;
  {
    float m = -3.0e38f;
    #pragma unroll
    for (int q=0;q<16;++q) m = fmaxf(m, scl[(ig*16+q)*17 + col]);
    pstat[ig*16+col] = m;
  }
  __syncthreads();
  if (t<16){
    float m = -3.0e38f;
    #pragma unroll
    for (int q=0;q<16;++q) m = fmaxf(m, pstat[q*16+t]);
    fstat[t] = m;
  }
  __syncthreads();
  {
    const float mj = fstat[col];
    float s = 0.f;
    #pragma unroll
    for (int q=0;q<16;++q) s += __expf(scl[(ig*16+q)*17 + col] - mj);
    pstat[ig*16+col] = s;
  }
  __syncthreads();
  if (t<16){
    float s = 0.f;
    #pragma unroll
    for (int q=0;q<16;++q) s += pstat[q*16+t];
    fstat[16+t] = 1.f/s;
  }
  __syncthreads();
  float* PTb = ws + WS_PT + b*65536;
  #pragma unroll
  for (int jj=0;jj<16;++jj){
    const float p = __expf(sc[jj] - fstat[jj]) * fstat[16+jj];
    PTb[(j0+jj)*256 + t] = p;                  // coalesced
  }
}

// ---------------- KB2: V1 = (P wv) * 1/sqrt(H) ----------------
// grid (4 iq, 16 b): lane = row, wave = c-group; wv via uniform s_loads.
__global__ __launch_bounds__(256) void kb2_v1(const float* __restrict__ wv,
                                              float* __restrict__ ws){
  __shared__ float PTl[64*65];
  const int b = blockIdx.y, iq = blockIdx.x;
  const int t = threadIdx.x;
  const int i = t&63;
  const int cg = __builtin_amdgcn_readfirstlane(t>>6);
  float acc[16];
  #pragma unroll
  for (int cc=0;cc<16;++cc) acc[cc]=0.f;
  const float* PTb = ws + WS_PT + b*65536 + iq*64;
  for (int jc=0;jc<4;++jc){
    __syncthreads();
    #pragma unroll
    for (int r=0;r<16;++r){
      const int e = t + 256*r;                 // jj = e>>6, ii = e&63
      PTl[(e>>6)*65 + (e&63)] = PTb[(jc*64 + (e>>6))*256 + (e&63)];
    }
    __syncthreads();
    #pragma unroll 4
    for (int jj=0;jj<64;++jj){
      const float p = PTl[jj*65 + i];          // conflict-free
      const float* wvr = wv + (jc*64+jj)*64 + cg*16;  // uniform -> s_load
      #pragma unroll
      for (int cc=0;cc<16;++cc)
        acc[cc] = fmaf(p, wvr[cc], acc[cc]);
    }
  }
  float* V1o = ws + WS_V1 + b*16384 + (iq*64+i)*64 + cg*16;
  #pragma unroll
  for (int cc=0;cc<16;++cc) V1o[cc] = acc[cc]*INV_SQRT_H;
}

// ---------------- KC: M K-partials = wc-slice @ V1-slice ----------------
// grid (4 kq, 16 b): lane = c, wave = o-group; wc via uniform s_loads.
__global__ __launch_bounds__(256) void kc_mpart(const float* __restrict__ wc,
                                                float* __restrict__ ws){
  __shared__ float V1l[4096];
  const int b = blockIdx.y, kq = blockIdx.x;
  const int t = threadIdx.x;
  const float* Vsrc = ws + WS_V1 + b*16384 + kq*4096;
  #pragma unroll
  for (int r=0;r<16;++r) V1l[t + 256*r] = Vsrc[t + 256*r];
  __syncthreads();
  const int c = t&63;
  const int og = __builtin_amdgcn_readfirstlane(t>>6);
  float acc[16];
  #pragma unroll
  for (int oo=0;oo<16;++oo) acc[oo]=0.f;
  #pragma unroll 4
  for (int i=0;i<64;++i){
    const float v = V1l[i*64 + c];             // conflict-free
    const float* wcr = wc + (og*16)*256 + kq*64 + i;  // uniform -> s_load
    #pragma unroll
    for (int oo=0;oo<16;++oo)
      acc[oo] = fmaf(wcr[oo*256], v, acc[oo]);
  }
  float* Mp = ws + WS_MPART + (b*4 + kq)*4096;
  #pragma unroll
  for (int oo=0;oo<16;++oo)
    Mp[(og*16+oo)*64 + c] = acc[oo];
}

// ---------------- KD: M rows + BN1 stats partials ----------------
__global__ __launch_bounds__(256) void kd_stats1(float* __restrict__ ws){
  __shared__ float Msub[16*65];
  __shared__ float Gl[64*67];
  __shared__ float Sxl[64];
  const int b = blockIdx.y, oq = blockIdx.x;
  const int t = threadIdx.x;
  const float* Mp = ws + WS_MPART + b*4*4096 + oq*1024;
  #pragma unroll
  for (int r=0;r<4;++r){
    const int e = t + 256*r;
    const float s = Mp[e] + Mp[4096+e] + Mp[2*4096+e] + Mp[3*4096+e];
    ws[WS_M + b*4096 + oq*1024 + e] = s;
    Msub[(e>>6)*65 + (e&63)] = s;
  }
  #pragma unroll 4
  for (int r=0;r<16;++r){
    const int e = t + 256*r;
    Gl[(e>>6)*67 + (e&63)] = ws[WS_G + b*4096 + e];
  }
  if (t<64) Sxl[t] = ws[WS_SX + b*64 + t];
  __syncthreads();
  const int o = t>>4, q = t&15;
  float d = 0.f;
  #pragma unroll
  for (int kk=0;kk<4;++kk){
    const int k = q*4+kk;
    float s = 0.f;
    #pragma unroll 4
    for (int c=0;c<64;++c) s = fmaf(Gl[k*67+c], Msub[o*65+c], s);
    d = fmaf(Msub[o*65+k], s, d);
  }
  d += __shfl_xor(d, 1, 16);
  d += __shfl_xor(d, 2, 16);
  d += __shfl_xor(d, 4, 16);
  d += __shfl_xor(d, 8, 16);
  if (q==0){
    float s1 = 0.f;
    #pragma unroll 4
    for (int c=0;c<64;++c) s1 = fmaf(Msub[o*65+c], Sxl[c], s1);
    atomicAdd(&ws[WS_STATS + oq*16 + o], s1);
    atomicAdd(&ws[WS_STATS + 64 + oq*16 + o], d);
  }
}

// ---------------- KE: N rows + BN2 stats partials ----------------
__global__ __launch_bounds__(256) void ke_n_stats2(const float* __restrict__ wl,
                                                   const float* __restrict__ g1,
                                                   float* __restrict__ ws){
  __shared__ float Ml[64*65];
  __shared__ float Gl[64*67];
  __shared__ float wls[16*65];
  __shared__ float Nsub[16*65];
  __shared__ float Sxl[64], a1l[64];
  const int b = blockIdx.y, oq = blockIdx.x;
  const int t = threadIdx.x;
  if (t<64){
    const float mean1 = ws[WS_STATS+t]*INV_BL;
    const float var1 = ws[WS_STATS+64+t]*INV_BL - mean1*mean1;
    a1l[t] = g1[t]*rsqrtf(var1 + EPSV);
    Sxl[t] = ws[WS_SX + b*64 + t];
  }
  #pragma unroll 4
  for (int r=0;r<16;++r){
    const int e = t + 256*r;
    Ml[(e>>6)*65 + (e&63)] = ws[WS_M + b*4096 + e];
    Gl[(e>>6)*67 + (e&63)] = ws[WS_G + b*4096 + e];
  }
  __syncthreads();
  #pragma unroll
  for (int r=0;r<4;++r){
    const int e = t + 256*r;
    wls[(e>>6)*65 + (e&63)] = wl[(oq*16 + (e>>6))*64 + (e&63)] * a1l[e&63];
  }
  __syncthreads();
  const int o = t>>4, q = t&15;
  const int row = oq*16 + o;
  {
    float acc[4];
    #pragma unroll
    for (int cc=0;cc<4;++cc) acc[cc]=0.f;
    #pragma unroll 4
    for (int k=0;k<64;++k){
      const float w = wls[o*65 + k];
      #pragma unroll
      for (int cc=0;cc<4;++cc)
        acc[cc] = fmaf(w, Ml[k*65 + q*4 + cc], acc[cc]);
    }
    #pragma unroll
    for (int cc=0;cc<4;++cc){
      const float nv = acc[cc] + wl[row*64 + q*4 + cc];
      ws[WS_N + b*4096 + o*64 + oq*1024 + q*4 + cc] = nv;
      Nsub[o*65 + q*4 + cc] = nv;
    }
  }
  __syncthreads();
  float d = 0.f;
  #pragma unroll
  for (int kk=0;kk<4;++kk){
    const int k = q*4+kk;
    float s = 0.f;
    #pragma unroll 4
    for (int c=0;c<64;++c) s = fmaf(Gl[k*67+c], Nsub[o*65+c], s);
    d = fmaf(Nsub[o*65+k], s, d);
  }
  d += __shfl_xor(d, 1, 16);
  d += __shfl_xor(d, 2, 16);
  d += __shfl_xor(d, 4, 16);
  d += __shfl_xor(d, 8, 16);
  if (q==0){
    float s2 = 0.f;
    #pragma unroll 4
    for (int c=0;c<64;++c) s2 = fmaf(Nsub[o*65+c], Sxl[c], s2);
    atomicAdd(&ws[WS_STATS + 128 + row], s2);
    atomicAdd(&ws[WS_STATS + 192 + row], d);
  }
}

// ---------------- K3: out = relu(a2*(N x) + e) ----------------
__global__ __launch_bounds__(256) void k3_out(const float* __restrict__ x,
                                              const float* __restrict__ g2,
                                              const float* __restrict__ b2,
                                              const float* __restrict__ ws,
                                              float* __restrict__ out){
  __shared__ float a2l[64], el[64];
  const int b = blockIdx.y, lc = blockIdx.x;
  const int t = threadIdx.x;
  if (t<64){
    const float mu = ws[WS_STATS+128+t]*INV_BL;
    const float var2 = ws[WS_STATS+192+t]*INV_BL - mu*mu;
    const float a2 = g2[t]*rsqrtf(var2 + EPSV);
    a2l[t] = a2;
    el[t] = b2[t] - a2*mu;
  }
  __syncthreads();
  const int w = __builtin_amdgcn_readfirstlane(t >> 6);
  const int lane = t & 63;
  const int l = lc*256 + 4*lane;
  const float* Np = ws + WS_N + b*4096 + w*1024;
  const float* xb = x + b*TC*TL + l;
  float4 acc[16];
  #pragma unroll
  for (int oo=0;oo<16;++oo){ acc[oo].x=0.f; acc[oo].y=0.f; acc[oo].z=0.f; acc[oo].w=0.f; }
  #pragma unroll 4
  for (int c=0;c<64;++c){
    const float4 xv = *(const float4*)(xb + c*TL);
    #pragma unroll
    for (int oo=0;oo<16;++oo){
      const float nv = Np[oo*64 + c];
      acc[oo].x = fmaf(nv, xv.x, acc[oo].x);
      acc[oo].y = fmaf(nv, xv.y, acc[oo].y);
      acc[oo].z = fmaf(nv, xv.z, acc[oo].z);
      acc[oo].w = fmaf(nv, xv.w, acc[oo].w);
    }
  }
  #pragma unroll
  for (int oo=0;oo<16;++oo){
    const float a2v = a2l[w*16+oo], ev = el[w*16+oo];
    float4 r;
    r.x = fmaxf(fmaf(a2v, acc[oo].x, ev), 0.f);
    r.y = fmaxf(fmaf(a2v, acc[oo].y, ev), 0.f);
    r.z = fmaxf(fmaf(a2v, acc[oo].z, ev), 0.f);
    r.w = fmaxf(fmaf(a2v, acc[oo].w, ev), 0.f);
    *(float4*)(out + (b*TC + w*16 + oo)*TL + l) = r;
  }
}

extern "C" void kernel_launch(void* const* d_in, const int* in_sizes, int n_in,
                              void* d_out, int out_size, void* d_ws, size_t ws_size,
                              hipStream_t stream){
  const float* x  = (const float*)d_in[0];
  const float* wk = (const float*)d_in[1];
  const float* wq = (const float*)d_in[2];
  const float* wv = (const float*)d_in[3];
  const float* wc = (const float*)d_in[4];
  const float* g1 = (const float*)d_in[5];
  /* b1 (d_in[6]) provably cancels through BN2 mean-subtraction */
  const float* wl = (const float*)d_in[7];
  const float* g2 = (const float*)d_in[8];
  const float* b2 = (const float*)d_in[9];
  float* out = (float*)d_out;
  float* ws  = (float*)d_ws;

  k1_gram    <<<dim3(16,16), 256, 0, stream>>>(x, ws);
  ka_reduce  <<<dim3(4,16),  256, 0, stream>>>(ws);
  ka2_s1t    <<<dim3(4,16),  256, 0, stream>>>(wq, ws);
  kb1_scores <<<dim3(16,16), 256, 0, stream>>>(wk, ws);
  kb2_v1     <<<dim3(4,16),  256, 0, stream>>>(wv, ws);
  kc_mpart   <<<dim3(4,16),  256, 0, stream>>>(wc, ws);
  kd_stats1  <<<dim3(4,16),  256, 0, stream>>>(ws);
  ke_n_stats2<<<dim3(4,16),  256, 0, stream>>>(wl, g1, ws);
  k3_out     <<<dim3(32,16), 256, 0, stream>>>(x, g2, b2, ws, out);
}